// Round 10
// baseline (168.066 us; speedup 1.0000x reference)
//
#include <hip/hip_runtime.h>

// CRF log-partition, MI355X — R10: R9 with the MFMA stream k-slice-interleaved.
// R9 measurement: matrix step ~2200 cyc, SAME as R8 despite 16 independent
// chains — because the source issued each tile's 4 K-chained MFMAs
// back-to-back and MFMA issue is in-order per wave: every dependent
// accumulate stalls ~25-30 cyc (48 pairs -> ~1800 cyc). Fix: ks-OUTER loop
// so consecutive MFMAs hit DIFFERENT accumulators; the dependent pair for
// any tile is 15 instructions (~75 cyc) apart -> latency hidden, step becomes
// issue-bound (~320 cyc MFMA + sbuf wait + repack tail ~= 700-900 cyc).
// Everything else is R9's validated (absmax 0.0) structure:
//   Z = alpha_a^T M1 M2 x_c; roles fwd/bwd/mat1/mat2; 16x16x32 MFMA;
//   intra-lane D->B repack with self-consistent kmap mu(q,e)=4q+(e&3)+16(e>>2);
//   per-wave sbuf row-scale; f32-exponent renorm (clamp +-24, o exact);
//   segments a=0.29T, b=T/2, c=T-a; vector roles = R2's validated recurrence.

#define LOG2E 1.4426950408889634f
#define LN2   0.6931471805599453f

#define LDS_BARRIER() asm volatile("s_waitcnt lgkmcnt(0)\n\ts_barrier" ::: "memory")
#define LGKM0() asm volatile("s_waitcnt lgkmcnt(0)" ::: "memory")

typedef float    f2  __attribute__((ext_vector_type(2)));
typedef float    f4  __attribute__((ext_vector_type(4)));
typedef unsigned u4  __attribute__((ext_vector_type(4)));
typedef _Float16 h2  __attribute__((ext_vector_type(2)));
typedef _Float16 h8  __attribute__((ext_vector_type(8)));

#define PKRTZ(a, b) __builtin_bit_cast(h2, __builtin_amdgcn_cvt_pkrtz((a), (b)))
#define BITS(x)     __builtin_bit_cast(unsigned, (x))

template <int CTRL>
__device__ __forceinline__ float dpp_f(float x) {
    return __int_as_float(
        __builtin_amdgcn_mov_dpp(__float_as_int(x), CTRL, 0xF, 0xF, false));
}

__global__ __launch_bounds__(256)
__attribute__((amdgpu_waves_per_eu(1, 1)))
void crf_fused(
    const float* __restrict__ emissions,   // [64, 512, 128]
    const float* __restrict__ transitions, // [128, 128]
    const float* __restrict__ start_t,     // [128]
    const float* __restrict__ end_t,       // [128]
    const int*   __restrict__ lengths,     // [64]
    float* __restrict__ wsV,               // [2][64][128]
    int*   __restrict__ wsO,               // [2][64]
    int*   __restrict__ wsMo,              // [2][64][4]
    _Float16* __restrict__ wsMh)           // [2][64][128][128]
{
    constexpr int N = 128;
    constexpr int L = 512;
    const int bid  = blockIdx.x;
    const int role = bid >> 6;   // 0 fwd, 1 bwd, 2 mat1, 3 mat2
    const int b    = bid & 63;
    const int tid  = threadIdx.x;

    const int len = lengths[b];
    const int T   = len - 1;
    const int qa  = (T * 29) / 100;          // vector/matrix balance point
    const int qb  = T >> 1;
    const int qc  = T - qa;
    const float* eb = emissions + (size_t)b * L * N;

    __shared__ alignas(16) float pbuf[2][80];     // vector roles
    __shared__ alignas(16) float sbuf[4][128];    // matrix roles (per wave)

    if (role < 2) {
        // ================= VECTOR ROLES (R2/R8/R9 validated code) ===========
        const bool isf = (role == 0);
        const int  g   = tid >> 2;
        const int  k   = tid & 3;

        h2 EA_0,  EA_1,  EA_2,  EA_3,  EA_4,  EA_5,  EA_6,  EA_7;
        h2 EA_8,  EA_9,  EA_10, EA_11, EA_12, EA_13, EA_14, EA_15;
        h2 EB_0,  EB_1,  EB_2,  EB_3,  EB_4,  EB_5,  EB_6,  EB_7;
        h2 EB_8,  EB_9,  EB_10, EB_11, EB_12, EB_13, EB_14, EB_15;
        if (isf) {
            const float* tb = transitions + (size_t)(32 * k) * N + 2 * g;
#define INIT_F(m)                                                              \
            {                                                                  \
                f2 r0 = *reinterpret_cast<const f2*>(tb + (size_t)(2 * (m)) * N); \
                f2 r1 = *reinterpret_cast<const f2*>(tb + (size_t)(2 * (m) + 1) * N); \
                EA_##m = PKRTZ(__builtin_amdgcn_exp2f(r0.x * LOG2E),           \
                               __builtin_amdgcn_exp2f(r1.x * LOG2E));          \
                EB_##m = PKRTZ(__builtin_amdgcn_exp2f(r0.y * LOG2E),           \
                               __builtin_amdgcn_exp2f(r1.y * LOG2E));          \
            }
            INIT_F(0)  INIT_F(1)  INIT_F(2)  INIT_F(3)
            INIT_F(4)  INIT_F(5)  INIT_F(6)  INIT_F(7)
            INIT_F(8)  INIT_F(9)  INIT_F(10) INIT_F(11)
            INIT_F(12) INIT_F(13) INIT_F(14) INIT_F(15)
#undef INIT_F
        } else {
            const float* ra_ = transitions + (size_t)(2 * g) * N + 32 * k;
            const float* rb_ = transitions + (size_t)(2 * g + 1) * N + 32 * k;
#define INIT_B(m)                                                              \
            {                                                                  \
                f2 r0 = *reinterpret_cast<const f2*>(ra_ + 2 * (m));           \
                f2 r1 = *reinterpret_cast<const f2*>(rb_ + 2 * (m));           \
                EA_##m = PKRTZ(__builtin_amdgcn_exp2f(r0.x * LOG2E),           \
                               __builtin_amdgcn_exp2f(r0.y * LOG2E));          \
                EB_##m = PKRTZ(__builtin_amdgcn_exp2f(r1.x * LOG2E),           \
                               __builtin_amdgcn_exp2f(r1.y * LOG2E));          \
            }
            INIT_B(0)  INIT_B(1)  INIT_B(2)  INIT_B(3)
            INIT_B(4)  INIT_B(5)  INIT_B(6)  INIT_B(7)
            INIT_B(8)  INIT_B(9)  INIT_B(10) INIT_B(11)
            INIT_B(12) INIT_B(13) INIT_B(14) INIT_B(15)
#undef INIT_B
        }

        int n_steps, e0, dstep; bool zfinal;
        if (isf) {
            n_steps = qa; e0 = 1; dstep = 1; zfinal = false;
        } else {
            int total = T - qc;
            n_steps = total > 0 ? total - 1 : 0;
            e0 = len - 2; if (e0 < 0) e0 = 0;
            dstep = -1;
            zfinal = total > 0;
        }

        int o = 0, cur = 0;
        float qA, qB;
        {
            const float* base = isf ? start_t : end_t;
            f2 bt = *reinterpret_cast<const f2*>(base + 2 * g);
            f2 ev;
            if (isf)         ev = *reinterpret_cast<const f2*>(eb + 2 * g);
            else if (zfinal) ev = *reinterpret_cast<const f2*>(eb + (size_t)(len - 1) * N + 2 * g);
            else           { ev.x = 0.f; ev.y = 0.f; }
            qA = __builtin_amdgcn_exp2f((bt.x + ev.x) * LOG2E);
            qB = __builtin_amdgcn_exp2f((bt.y + ev.y) * LOG2E);
            if (k == 0)
                pbuf[0][(g >> 4) * 20 + (g & 15)] =
                    __builtin_bit_cast(float, PKRTZ(qA, qB));
        }
        LDS_BARRIER();

        auto eidx = [&](int n) {
            int nn2 = (n < n_steps) ? n : (n_steps - 1);
            if (nn2 < 0) nn2 = 0;
            return e0 + dstep * nn2;
        };
        auto ldE = [&](int tt) {
            return *reinterpret_cast<const f2*>(eb + (size_t)tt * N + 2 * g);
        };

        auto STEP = [&](f2 ecur) {
            float q0w = pbuf[cur][0];
            const float4* pv = reinterpret_cast<const float4*>(&pbuf[cur][k * 20]);
            float4 Qa = pv[0], Qb = pv[1], Qc = pv[2], Qd = pv[3];

            unsigned u0 = __float_as_uint(q0w);
            int eS = (int)((u0 >> 10) & 0x1Fu) - 15;
            o += eS;
            float feS = (float)eS;
            float esA = __builtin_amdgcn_exp2f(ecur.x * LOG2E - feS);
            float esB = __builtin_amdgcn_exp2f(ecur.y * LOG2E - feS);

            float aA0 = 0.f, aA1 = 0.f, aB0 = 0.f, aB1 = 0.f;
#define D0(m_, Qc_)                                                            \
            {                                                                  \
                h2 pm = __builtin_bit_cast(h2, Qc_);                           \
                aA0 = __builtin_amdgcn_fdot2(pm, EA_##m_, aA0, false);         \
                aB0 = __builtin_amdgcn_fdot2(pm, EB_##m_, aB0, false);         \
            }
#define D1(m_, Qc_)                                                            \
            {                                                                  \
                h2 pm = __builtin_bit_cast(h2, Qc_);                           \
                aA1 = __builtin_amdgcn_fdot2(pm, EA_##m_, aA1, false);         \
                aB1 = __builtin_amdgcn_fdot2(pm, EB_##m_, aB1, false);         \
            }
            D0(0,  Qa.x) D1(1,  Qa.y) D0(2,  Qa.z) D1(3,  Qa.w)
            D0(4,  Qb.x) D1(5,  Qb.y) D0(6,  Qb.z) D1(7,  Qb.w)
            D0(8,  Qc.x) D1(9,  Qc.y) D0(10, Qc.z) D1(11, Qc.w)
            D0(12, Qd.x) D1(13, Qd.y) D0(14, Qd.z) D1(15, Qd.w)
#undef D0
#undef D1
            float dA = aA0 + aA1;
            float dB = aB0 + aB1;
            dA += dpp_f<0xB1>(dA); dB += dpp_f<0xB1>(dB);
            dA += dpp_f<0x4E>(dA); dB += dpp_f<0x4E>(dB);

            qA = esA * dA;
            qB = esB * dB;
            cur ^= 1;
            if (k == 0)
                pbuf[cur][(g >> 4) * 20 + (g & 15)] =
                    __builtin_bit_cast(float, PKRTZ(qA, qB));
            LDS_BARRIER();
        };

        f2 ra = ldE(eidx(0));
        f2 rb = ldE(eidx(1));
        f2 rc = ldE(eidx(2));
        f2 rd = ldE(eidx(3));

        int n = 0;
        while (n < n_steps) {
            STEP(ra); ra = ldE(eidx(n + 4)); ++n; if (n >= n_steps) break;
            STEP(rb); rb = ldE(eidx(n + 4)); ++n; if (n >= n_steps) break;
            STEP(rc); rc = ldE(eidx(n + 4)); ++n; if (n >= n_steps) break;
            STEP(rd); rd = ldE(eidx(n + 4)); ++n;
        }
        if (zfinal) { f2 z; z.x = 0.f; z.y = 0.f; STEP(z); }

        float* wv = wsV + (size_t)(role * 64 + b) * 128;
        if (k == 0) {
            f2 q; q.x = qA; q.y = qB;
            *reinterpret_cast<f2*>(wv + 2 * g) = q;
        }
        if (tid == 0) wsO[role * 64 + b] = o;

    } else {
        // ================= MATRIX ROLES: 16x16x32 MFMA, ks-OUTER stream =====
        const int w     = tid >> 6;       // wave = strip cols [32w, 32w+32)
        const int lidx  = tid & 63;
        const int lq    = (tid >> 4) & 3; // lane>>4
        const int m15   = tid & 15;       // lane&15
        const int matid = role - 2;
        const int tlo   = matid ? qb : qa;
        const int nm    = matid ? (qc - qb) : (qb - qa);

        // ---- A = E^T fragments (const): Afr[rt][ks], A[m][k] = exp(T[kg][mg])
        // mg = 16rt + m15, kg = 32ks + mu(lq,e), mu = 4lq + (e&3) + 16*(e>>2)
        h8 Afr[8][4];
        #pragma unroll
        for (int rt = 0; rt < 8; ++rt) {
            #pragma unroll
            for (int ks = 0; ks < 4; ++ks) {
                u4 au;
                #pragma unroll
                for (int ep = 0; ep < 4; ++ep) {
                    int ee0 = 2 * ep, ee1 = 2 * ep + 1;
                    int k0 = 32 * ks + 4 * lq + (ee0 & 3) + 16 * (ee0 >> 2);
                    int k1 = 32 * ks + 4 * lq + (ee1 & 3) + 16 * (ee1 >> 2);
                    float v0 = __builtin_amdgcn_exp2f(
                        transitions[k0 * N + 16 * rt + m15] * LOG2E);
                    float v1 = __builtin_amdgcn_exp2f(
                        transitions[k1 * N + 16 * rt + m15] * LOG2E);
                    au[ep] = BITS(PKRTZ(v0, v1));
                }
                Afr[rt][ks] = __builtin_bit_cast(h8, au);
            }
        }

        // ---- B init = identity strip
        h8 Bf[4][2];
        #pragma unroll
        for (int ks = 0; ks < 4; ++ks) {
            #pragma unroll
            for (int ct = 0; ct < 2; ++ct) {
                u4 bu; bu[0] = 0u; bu[1] = 0u; bu[2] = 0u; bu[3] = 0u;
                #pragma unroll
                for (int e = 0; e < 8; ++e) {
                    int kk = 32 * ks + 4 * lq + (e & 3) + 16 * (e >> 2);
                    if (kk == 32 * w + 16 * ct + m15)
                        bu[e >> 1] |= 0x3C00u << (16 * (e & 1));
                }
                Bf[ks][ct] = __builtin_bit_cast(h8, bu);
            }
        }
        int o = 0;

        auto ldEm = [&](int q) {
            int qq = q; if (qq > nm - 1) qq = nm - 1; if (qq < 0) qq = 0;
            int t = tlo + 1 + qq;
            return *reinterpret_cast<const f2*>(eb + (size_t)t * N + 2 * lidx);
        };

        auto STEPm = [&](f2 ev) {
            // s broadcast within wave via sbuf (write own pair, read b128 runs)
            f2 sp;
            sp.x = __builtin_amdgcn_exp2f(ev.x * LOG2E);
            sp.y = __builtin_amdgcn_exp2f(ev.y * LOG2E);
            *reinterpret_cast<f2*>(&sbuf[w][2 * lidx]) = sp;
            LGKM0();
            f4 srt[8];
            #pragma unroll
            for (int rt = 0; rt < 8; ++rt)
                srt[rt] = *reinterpret_cast<const f4*>(&sbuf[w][16 * rt + 4 * lq]);

            // 64 MFMA, ks-OUTER: consecutive instructions hit different
            // accumulators; dependent pair for a tile is 16 apart (~75 cyc)
            f4 Dr[8][2];
            #pragma unroll
            for (int rt = 0; rt < 8; ++rt) {
                #pragma unroll
                for (int ct = 0; ct < 2; ++ct) {
                    f4 z = {0.f, 0.f, 0.f, 0.f};
                    Dr[rt][ct] = z;
                }
            }
            #pragma unroll
            for (int ks = 0; ks < 4; ++ks) {
                #pragma unroll
                for (int rt = 0; rt < 8; ++rt) {
                    #pragma unroll
                    for (int ct = 0; ct < 2; ++ct)
                        Dr[rt][ct] = __builtin_amdgcn_mfma_f32_16x16x32_f16(
                            Afr[rt][ks], Bf[ks][ct], Dr[rt][ct], 0, 0, 0);
                }
            }

            // renorm from reference element (lane 0: row 0, col 32w)
            int rb_ = __builtin_amdgcn_readfirstlane(__float_as_int(Dr[0][0][0]));
            int ex = (int)(((unsigned)rb_ >> 23) & 255u) - 127;
            if (ex > 24) ex = 24; if (ex < -24) ex = -24;
            o += ex;
            float sc = __int_as_float((unsigned)(127 - ex) << 23);

            f4 ssr[8];
            #pragma unroll
            for (int rt = 0; rt < 8; ++rt) ssr[rt] = srt[rt] * sc;

            // intra-lane repack D -> B (slot e <- D[2ks+(e>>2)][ct] reg e&3)
            #pragma unroll
            for (int ks = 0; ks < 4; ++ks) {
                #pragma unroll
                for (int ct = 0; ct < 2; ++ct) {
                    u4 bu;
                    bu[0] = BITS(PKRTZ(Dr[2*ks][ct][0]   * ssr[2*ks][0],
                                       Dr[2*ks][ct][1]   * ssr[2*ks][1]));
                    bu[1] = BITS(PKRTZ(Dr[2*ks][ct][2]   * ssr[2*ks][2],
                                       Dr[2*ks][ct][3]   * ssr[2*ks][3]));
                    bu[2] = BITS(PKRTZ(Dr[2*ks+1][ct][0] * ssr[2*ks+1][0],
                                       Dr[2*ks+1][ct][1] * ssr[2*ks+1][1]));
                    bu[3] = BITS(PKRTZ(Dr[2*ks+1][ct][2] * ssr[2*ks+1][2],
                                       Dr[2*ks+1][ct][3] * ssr[2*ks+1][3]));
                    Bf[ks][ct] = __builtin_bit_cast(h8, bu);
                }
            }
        };

        f2 ra = ldEm(0), rb = ldEm(1);
        int q = 0;
        while (q + 1 < nm) {
            STEPm(ra); ra = ldEm(q + 2);
            STEPm(rb); rb = ldEm(q + 3);
            q += 2;
        }
        if (q < nm) STEPm(ra);

        // ---- store strip as M_store[c][row]
        {
            _Float16* wmb = wsMh + (size_t)(matid * 64 + b) * 128 * 128;
            #pragma unroll
            for (int ct = 0; ct < 2; ++ct) {
                _Float16* wm = wmb + (size_t)(32 * w + 16 * ct + m15) * 128;
                #pragma unroll
                for (int ks = 0; ks < 4; ++ks) {
                    u4 bu = __builtin_bit_cast(u4, Bf[ks][ct]);
                    #pragma unroll
                    for (int e = 0; e < 8; ++e) {
                        int row = 32 * ks + 4 * lq + (e & 3) + 16 * (e >> 2);
                        unsigned dw = bu[e >> 1];
                        unsigned short us = (unsigned short)((e & 1) ? (dw >> 16)
                                                                     : (dw & 0xFFFFu));
                        wm[row] = __builtin_bit_cast(_Float16, us);
                    }
                }
            }
        }
        if (lidx == 0) wsMo[(matid * 64 + b) * 4 + w] = o;
    }
}

__global__ __launch_bounds__(128)
void crf_combine(const float* __restrict__ wsV, const int* __restrict__ wsO,
                 const int* __restrict__ wsMo, const _Float16* __restrict__ wsMh,
                 float* __restrict__ out)
{
    const int b = blockIdx.x;
    const int j = threadIdx.x;   // 0..127
    __shared__ float stage[128];
    __shared__ float redw[2];

    int o10 = wsMo[(0 * 64 + b) * 4 + 0], o11 = wsMo[(0 * 64 + b) * 4 + 1];
    int o12 = wsMo[(0 * 64 + b) * 4 + 2], o13 = wsMo[(0 * 64 + b) * 4 + 3];
    int o20 = wsMo[(1 * 64 + b) * 4 + 0], o21 = wsMo[(1 * 64 + b) * 4 + 1];
    int o22 = wsMo[(1 * 64 + b) * 4 + 2], o23 = wsMo[(1 * 64 + b) * 4 + 3];
    int O1 = max(max(o10, o11), max(o12, o13));
    int O2 = max(max(o20, o21), max(o22, o23));

    float al = wsV[(size_t)(0 * 64 + b) * 128 + j];
    int r1 = wsMo[(0 * 64 + b) * 4 + (j >> 5)];
    stage[j] = al * __builtin_amdgcn_exp2f((float)(r1 - O1));
    __syncthreads();

    float v1 = 0.f;
    const _Float16* M1 = wsMh + (size_t)(0 * 64 + b) * 128 * 128;
    #pragma unroll 8
    for (int i = 0; i < 128; ++i)
        v1 += stage[i] * (float)M1[(size_t)i * 128 + j];
    __syncthreads();

    int r2 = wsMo[(1 * 64 + b) * 4 + (j >> 5)];
    stage[j] = v1 * __builtin_amdgcn_exp2f((float)(r2 - O2));
    __syncthreads();

    float v2 = 0.f;
    const _Float16* M2 = wsMh + (size_t)(1 * 64 + b) * 128 * 128;
    #pragma unroll 8
    for (int i = 0; i < 128; ++i)
        v2 += stage[i] * (float)M2[(size_t)i * 128 + j];

    float term = v2 * wsV[(size_t)(1 * 64 + b) * 128 + j];
    #pragma unroll
    for (int s = 1; s < 64; s <<= 1) term += __shfl_xor(term, s);
    if ((j & 63) == 0) redw[j >> 6] = term;
    __syncthreads();
    if (j == 0) {
        float V = redw[0] + redw[1];
        out[b] = LN2 * ((float)(wsO[b] + wsO[64 + b] + O1 + O2) +
                        __builtin_amdgcn_logf(V));
    }
}

extern "C" void kernel_launch(void* const* d_in, const int* in_sizes, int n_in,
                              void* d_out, int out_size, void* d_ws, size_t ws_size,
                              hipStream_t stream) {
    const float* emissions   = (const float*)d_in[0];
    const float* transitions = (const float*)d_in[1];
    const float* start_t     = (const float*)d_in[2];
    const float* end_t       = (const float*)d_in[3];
    const int*   lengths     = (const int*)d_in[4];
    float* out = (float*)d_out;

    float*    wsV  = (float*)d_ws;                          // 65536 B
    int*      wsO  = (int*)((char*)d_ws + 65536);           // 512 B
    int*      wsMo = (int*)((char*)d_ws + 66048);           // 2048 B
    _Float16* wsMh = (_Float16*)((char*)d_ws + 68096);      // 4 MB

    crf_fused<<<dim3(256), dim3(256), 0, stream>>>(
        emissions, transitions, start_t, end_t, lengths, wsV, wsO, wsMo, wsMh);
    crf_combine<<<dim3(64), dim3(128), 0, stream>>>(wsV, wsO, wsMo, wsMh, out);
}

// Round 11
// 136.737 us; speedup vs baseline: 1.2291x; 1.2291x over previous
//
#include <hip/hip_runtime.h>

// CRF log-partition, MI355X — R11: R10 rebalanced to the MEASURED step-cost
// ratio + double-buffered sbuf pipeline.
// Evidence from R8/R9/R10: matrix step = 2210 cyc INVARIANT to MFMA shape and
// instruction order -> not dependency-bound; cost = MFMA block + constant
// serial skeleton (sbuf write->lgkm->read latency at the step front, repack,
// renorm). Two changes, both evidence-driven:
//  1. Segment split from measured ratio 2210/648=3.4: qa=0.386T (was 0.29T).
//     Equalizes vector pole (qa*648) and matrix pole (nm*2210): 233k->126k cyc.
//  2. sbuf double-buffered: step n reads s(n) (written >=1 full step earlier,
//     latency hidden under step n-1's MFMAs), and issues the write of s(n+1)
//     BEFORE its own MFMA block -> the write->read LDS roundtrip leaves the
//     serial path. Single wave, in-order LDS, compiler-inserted waits.
// Everything else is R9/R10's twice-validated (absmax 0.0) structure:
// Z = alpha_a^T M1 M2 x_c; 16x16x32 MFMA ks-outer; intra-lane D->B repack
// (kmap mu(q,e)=4q+(e&3)+16(e>>2)); f32-exponent renorm clamp +-24;
// vector roles = R2's validated recurrence; combine unchanged.

#define LOG2E 1.4426950408889634f
#define LN2   0.6931471805599453f

#define LDS_BARRIER() asm volatile("s_waitcnt lgkmcnt(0)\n\ts_barrier" ::: "memory")

typedef float    f2  __attribute__((ext_vector_type(2)));
typedef float    f4  __attribute__((ext_vector_type(4)));
typedef unsigned u4  __attribute__((ext_vector_type(4)));
typedef _Float16 h2  __attribute__((ext_vector_type(2)));
typedef _Float16 h8  __attribute__((ext_vector_type(8)));

#define PKRTZ(a, b) __builtin_bit_cast(h2, __builtin_amdgcn_cvt_pkrtz((a), (b)))
#define BITS(x)     __builtin_bit_cast(unsigned, (x))

template <int CTRL>
__device__ __forceinline__ float dpp_f(float x) {
    return __int_as_float(
        __builtin_amdgcn_mov_dpp(__float_as_int(x), CTRL, 0xF, 0xF, false));
}

__global__ __launch_bounds__(256)
__attribute__((amdgpu_waves_per_eu(1, 1)))
void crf_fused(
    const float* __restrict__ emissions,   // [64, 512, 128]
    const float* __restrict__ transitions, // [128, 128]
    const float* __restrict__ start_t,     // [128]
    const float* __restrict__ end_t,       // [128]
    const int*   __restrict__ lengths,     // [64]
    float* __restrict__ wsV,               // [2][64][128]
    int*   __restrict__ wsO,               // [2][64]
    int*   __restrict__ wsMo,              // [2][64][4]
    _Float16* __restrict__ wsMh)           // [2][64][128][128]
{
    constexpr int N = 128;
    constexpr int L = 512;
    const int bid  = blockIdx.x;
    const int role = bid >> 6;   // 0 fwd, 1 bwd, 2 mat1, 3 mat2
    const int b    = bid & 63;
    const int tid  = threadIdx.x;

    const int len = lengths[b];
    const int T   = len - 1;
    const int qa  = (T * 386) / 1000;        // measured-ratio balance point
    const int qb  = T >> 1;
    const int qc  = T - qa;
    const float* eb = emissions + (size_t)b * L * N;

    __shared__ alignas(16) float pbuf[2][80];        // vector roles
    __shared__ alignas(16) float sbuf[4][2][128];    // matrix roles, dbuf

    if (role < 2) {
        // ================= VECTOR ROLES (R2/R8/R9 validated code) ===========
        const bool isf = (role == 0);
        const int  g   = tid >> 2;
        const int  k   = tid & 3;

        h2 EA_0,  EA_1,  EA_2,  EA_3,  EA_4,  EA_5,  EA_6,  EA_7;
        h2 EA_8,  EA_9,  EA_10, EA_11, EA_12, EA_13, EA_14, EA_15;
        h2 EB_0,  EB_1,  EB_2,  EB_3,  EB_4,  EB_5,  EB_6,  EB_7;
        h2 EB_8,  EB_9,  EB_10, EB_11, EB_12, EB_13, EB_14, EB_15;
        if (isf) {
            const float* tb = transitions + (size_t)(32 * k) * N + 2 * g;
#define INIT_F(m)                                                              \
            {                                                                  \
                f2 r0 = *reinterpret_cast<const f2*>(tb + (size_t)(2 * (m)) * N); \
                f2 r1 = *reinterpret_cast<const f2*>(tb + (size_t)(2 * (m) + 1) * N); \
                EA_##m = PKRTZ(__builtin_amdgcn_exp2f(r0.x * LOG2E),           \
                               __builtin_amdgcn_exp2f(r1.x * LOG2E));          \
                EB_##m = PKRTZ(__builtin_amdgcn_exp2f(r0.y * LOG2E),           \
                               __builtin_amdgcn_exp2f(r1.y * LOG2E));          \
            }
            INIT_F(0)  INIT_F(1)  INIT_F(2)  INIT_F(3)
            INIT_F(4)  INIT_F(5)  INIT_F(6)  INIT_F(7)
            INIT_F(8)  INIT_F(9)  INIT_F(10) INIT_F(11)
            INIT_F(12) INIT_F(13) INIT_F(14) INIT_F(15)
#undef INIT_F
        } else {
            const float* ra_ = transitions + (size_t)(2 * g) * N + 32 * k;
            const float* rb_ = transitions + (size_t)(2 * g + 1) * N + 32 * k;
#define INIT_B(m)                                                              \
            {                                                                  \
                f2 r0 = *reinterpret_cast<const f2*>(ra_ + 2 * (m));           \
                f2 r1 = *reinterpret_cast<const f2*>(rb_ + 2 * (m));           \
                EA_##m = PKRTZ(__builtin_amdgcn_exp2f(r0.x * LOG2E),           \
                               __builtin_amdgcn_exp2f(r0.y * LOG2E));          \
                EB_##m = PKRTZ(__builtin_amdgcn_exp2f(r1.x * LOG2E),           \
                               __builtin_amdgcn_exp2f(r1.y * LOG2E));          \
            }
            INIT_B(0)  INIT_B(1)  INIT_B(2)  INIT_B(3)
            INIT_B(4)  INIT_B(5)  INIT_B(6)  INIT_B(7)
            INIT_B(8)  INIT_B(9)  INIT_B(10) INIT_B(11)
            INIT_B(12) INIT_B(13) INIT_B(14) INIT_B(15)
#undef INIT_B
        }

        int n_steps, e0, dstep; bool zfinal;
        if (isf) {
            n_steps = qa; e0 = 1; dstep = 1; zfinal = false;
        } else {
            int total = T - qc;
            n_steps = total > 0 ? total - 1 : 0;
            e0 = len - 2; if (e0 < 0) e0 = 0;
            dstep = -1;
            zfinal = total > 0;
        }

        int o = 0, cur = 0;
        float qA, qB;
        {
            const float* base = isf ? start_t : end_t;
            f2 bt = *reinterpret_cast<const f2*>(base + 2 * g);
            f2 ev;
            if (isf)         ev = *reinterpret_cast<const f2*>(eb + 2 * g);
            else if (zfinal) ev = *reinterpret_cast<const f2*>(eb + (size_t)(len - 1) * N + 2 * g);
            else           { ev.x = 0.f; ev.y = 0.f; }
            qA = __builtin_amdgcn_exp2f((bt.x + ev.x) * LOG2E);
            qB = __builtin_amdgcn_exp2f((bt.y + ev.y) * LOG2E);
            if (k == 0)
                pbuf[0][(g >> 4) * 20 + (g & 15)] =
                    __builtin_bit_cast(float, PKRTZ(qA, qB));
        }
        LDS_BARRIER();

        auto eidx = [&](int n) {
            int nn2 = (n < n_steps) ? n : (n_steps - 1);
            if (nn2 < 0) nn2 = 0;
            return e0 + dstep * nn2;
        };
        auto ldE = [&](int tt) {
            return *reinterpret_cast<const f2*>(eb + (size_t)tt * N + 2 * g);
        };

        auto STEP = [&](f2 ecur) {
            float q0w = pbuf[cur][0];
            const float4* pv = reinterpret_cast<const float4*>(&pbuf[cur][k * 20]);
            float4 Qa = pv[0], Qb = pv[1], Qc = pv[2], Qd = pv[3];

            unsigned u0 = __float_as_uint(q0w);
            int eS = (int)((u0 >> 10) & 0x1Fu) - 15;
            o += eS;
            float feS = (float)eS;
            float esA = __builtin_amdgcn_exp2f(ecur.x * LOG2E - feS);
            float esB = __builtin_amdgcn_exp2f(ecur.y * LOG2E - feS);

            float aA0 = 0.f, aA1 = 0.f, aB0 = 0.f, aB1 = 0.f;
#define D0(m_, Qc_)                                                            \
            {                                                                  \
                h2 pm = __builtin_bit_cast(h2, Qc_);                           \
                aA0 = __builtin_amdgcn_fdot2(pm, EA_##m_, aA0, false);         \
                aB0 = __builtin_amdgcn_fdot2(pm, EB_##m_, aB0, false);         \
            }
#define D1(m_, Qc_)                                                            \
            {                                                                  \
                h2 pm = __builtin_bit_cast(h2, Qc_);                           \
                aA1 = __builtin_amdgcn_fdot2(pm, EA_##m_, aA1, false);         \
                aB1 = __builtin_amdgcn_fdot2(pm, EB_##m_, aB1, false);         \
            }
            D0(0,  Qa.x) D1(1,  Qa.y) D0(2,  Qa.z) D1(3,  Qa.w)
            D0(4,  Qb.x) D1(5,  Qb.y) D0(6,  Qb.z) D1(7,  Qb.w)
            D0(8,  Qc.x) D1(9,  Qc.y) D0(10, Qc.z) D1(11, Qc.w)
            D0(12, Qd.x) D1(13, Qd.y) D0(14, Qd.z) D1(15, Qd.w)
#undef D0
#undef D1
            float dA = aA0 + aA1;
            float dB = aB0 + aB1;
            dA += dpp_f<0xB1>(dA); dB += dpp_f<0xB1>(dB);
            dA += dpp_f<0x4E>(dA); dB += dpp_f<0x4E>(dB);

            qA = esA * dA;
            qB = esB * dB;
            cur ^= 1;
            if (k == 0)
                pbuf[cur][(g >> 4) * 20 + (g & 15)] =
                    __builtin_bit_cast(float, PKRTZ(qA, qB));
            LDS_BARRIER();
        };

        f2 ra = ldE(eidx(0));
        f2 rb = ldE(eidx(1));
        f2 rc = ldE(eidx(2));
        f2 rd = ldE(eidx(3));

        int n = 0;
        while (n < n_steps) {
            STEP(ra); ra = ldE(eidx(n + 4)); ++n; if (n >= n_steps) break;
            STEP(rb); rb = ldE(eidx(n + 4)); ++n; if (n >= n_steps) break;
            STEP(rc); rc = ldE(eidx(n + 4)); ++n; if (n >= n_steps) break;
            STEP(rd); rd = ldE(eidx(n + 4)); ++n;
        }
        if (zfinal) { f2 z; z.x = 0.f; z.y = 0.f; STEP(z); }

        float* wv = wsV + (size_t)(role * 64 + b) * 128;
        if (k == 0) {
            f2 q; q.x = qA; q.y = qB;
            *reinterpret_cast<f2*>(wv + 2 * g) = q;
        }
        if (tid == 0) wsO[role * 64 + b] = o;

    } else {
        // ========== MATRIX ROLES: 16x16x32, ks-outer, dbuf sbuf pipeline ====
        const int w     = tid >> 6;       // wave = strip cols [32w, 32w+32)
        const int lidx  = tid & 63;
        const int lq    = (tid >> 4) & 3; // lane>>4
        const int m15   = tid & 15;       // lane&15
        const int matid = role - 2;
        const int tlo   = matid ? qb : qa;
        const int nm    = matid ? (qc - qb) : (qb - qa);

        // ---- A = E^T fragments (const): Afr[rt][ks], A[m][k] = exp(T[kg][mg])
        // mg = 16rt + m15, kg = 32ks + mu(lq,e), mu = 4lq + (e&3) + 16*(e>>2)
        h8 Afr[8][4];
        #pragma unroll
        for (int rt = 0; rt < 8; ++rt) {
            #pragma unroll
            for (int ks = 0; ks < 4; ++ks) {
                u4 au;
                #pragma unroll
                for (int ep = 0; ep < 4; ++ep) {
                    int ee0 = 2 * ep, ee1 = 2 * ep + 1;
                    int k0 = 32 * ks + 4 * lq + (ee0 & 3) + 16 * (ee0 >> 2);
                    int k1 = 32 * ks + 4 * lq + (ee1 & 3) + 16 * (ee1 >> 2);
                    float v0 = __builtin_amdgcn_exp2f(
                        transitions[k0 * N + 16 * rt + m15] * LOG2E);
                    float v1 = __builtin_amdgcn_exp2f(
                        transitions[k1 * N + 16 * rt + m15] * LOG2E);
                    au[ep] = BITS(PKRTZ(v0, v1));
                }
                Afr[rt][ks] = __builtin_bit_cast(h8, au);
            }
        }

        // ---- B init = identity strip
        h8 Bf[4][2];
        #pragma unroll
        for (int ks = 0; ks < 4; ++ks) {
            #pragma unroll
            for (int ct = 0; ct < 2; ++ct) {
                u4 bu; bu[0] = 0u; bu[1] = 0u; bu[2] = 0u; bu[3] = 0u;
                #pragma unroll
                for (int e = 0; e < 8; ++e) {
                    int kk = 32 * ks + 4 * lq + (e & 3) + 16 * (e >> 2);
                    if (kk == 32 * w + 16 * ct + m15)
                        bu[e >> 1] |= 0x3C00u << (16 * (e & 1));
                }
                Bf[ks][ct] = __builtin_bit_cast(h8, bu);
            }
        }
        int o = 0;

        auto ldEm = [&](int q) {
            int qq = q; if (qq > nm - 1) qq = nm - 1; if (qq < 0) qq = 0;
            int t = tlo + 1 + qq;
            return *reinterpret_cast<const f2*>(eb + (size_t)t * N + 2 * lidx);
        };

        // write s(ev) into sbuf[w][buf]
        auto SPWRITE = [&](f2 ev, int buf) {
            f2 sp;
            sp.x = __builtin_amdgcn_exp2f(ev.x * LOG2E);
            sp.y = __builtin_amdgcn_exp2f(ev.y * LOG2E);
            *reinterpret_cast<f2*>(&sbuf[w][buf][2 * lidx]) = sp;
        };

        // step n: consume sbuf[bufp] (written a full step ago), issue the
        // write of s(n+1) BEFORE the MFMA block (other buffer, no conflict)
        auto STEPm = [&](f2 evnext, int bufp) {
            f4 srt[8];
            #pragma unroll
            for (int rt = 0; rt < 8; ++rt)
                srt[rt] = *reinterpret_cast<const f4*>(
                    &sbuf[w][bufp][16 * rt + 4 * lq]);
            SPWRITE(evnext, bufp ^ 1);

            // 64 MFMA, ks-outer (validated R10)
            f4 Dr[8][2];
            #pragma unroll
            for (int rt = 0; rt < 8; ++rt) {
                #pragma unroll
                for (int ct = 0; ct < 2; ++ct) {
                    f4 z = {0.f, 0.f, 0.f, 0.f};
                    Dr[rt][ct] = z;
                }
            }
            #pragma unroll
            for (int ks = 0; ks < 4; ++ks) {
                #pragma unroll
                for (int rt = 0; rt < 8; ++rt) {
                    #pragma unroll
                    for (int ct = 0; ct < 2; ++ct)
                        Dr[rt][ct] = __builtin_amdgcn_mfma_f32_16x16x32_f16(
                            Afr[rt][ks], Bf[ks][ct], Dr[rt][ct], 0, 0, 0);
                }
            }

            // renorm from reference element (lane 0: row 0, col 32w)
            int rb_ = __builtin_amdgcn_readfirstlane(__float_as_int(Dr[0][0][0]));
            int ex = (int)(((unsigned)rb_ >> 23) & 255u) - 127;
            if (ex > 24) ex = 24; if (ex < -24) ex = -24;
            o += ex;
            float sc = __int_as_float((unsigned)(127 - ex) << 23);

            f4 ssr[8];
            #pragma unroll
            for (int rt = 0; rt < 8; ++rt) ssr[rt] = srt[rt] * sc;

            // intra-lane repack D -> B (slot e <- D[2ks+(e>>2)][ct] reg e&3)
            #pragma unroll
            for (int ks = 0; ks < 4; ++ks) {
                #pragma unroll
                for (int ct = 0; ct < 2; ++ct) {
                    u4 bu;
                    bu[0] = BITS(PKRTZ(Dr[2*ks][ct][0]   * ssr[2*ks][0],
                                       Dr[2*ks][ct][1]   * ssr[2*ks][1]));
                    bu[1] = BITS(PKRTZ(Dr[2*ks][ct][2]   * ssr[2*ks][2],
                                       Dr[2*ks][ct][3]   * ssr[2*ks][3]));
                    bu[2] = BITS(PKRTZ(Dr[2*ks+1][ct][0] * ssr[2*ks+1][0],
                                       Dr[2*ks+1][ct][1] * ssr[2*ks+1][1]));
                    bu[3] = BITS(PKRTZ(Dr[2*ks+1][ct][2] * ssr[2*ks+1][2],
                                       Dr[2*ks+1][ct][3] * ssr[2*ks+1][3]));
                    Bf[ks][ct] = __builtin_bit_cast(h8, bu);
                }
            }
        };

        if (nm > 0) {
            SPWRITE(ldEm(0), 0);             // s(0) into buffer 0
            f2 ra = ldEm(1), rb = ldEm(2);   // ev ring, one step ahead
            int q = 0, bufp = 0;
            while (q + 1 < nm) {
                STEPm(ra, bufp); bufp ^= 1; ra = ldEm(q + 3);
                STEPm(rb, bufp); bufp ^= 1; rb = ldEm(q + 4);
                q += 2;
            }
            if (q < nm) STEPm(ra, bufp);
        }

        // ---- store strip as M_store[c][row]
        {
            _Float16* wmb = wsMh + (size_t)(matid * 64 + b) * 128 * 128;
            #pragma unroll
            for (int ct = 0; ct < 2; ++ct) {
                _Float16* wm = wmb + (size_t)(32 * w + 16 * ct + m15) * 128;
                #pragma unroll
                for (int ks = 0; ks < 4; ++ks) {
                    u4 bu = __builtin_bit_cast(u4, Bf[ks][ct]);
                    #pragma unroll
                    for (int e = 0; e < 8; ++e) {
                        int row = 32 * ks + 4 * lq + (e & 3) + 16 * (e >> 2);
                        unsigned dw = bu[e >> 1];
                        unsigned short us = (unsigned short)((e & 1) ? (dw >> 16)
                                                                     : (dw & 0xFFFFu));
                        wm[row] = __builtin_bit_cast(_Float16, us);
                    }
                }
            }
        }
        if (lidx == 0) wsMo[(matid * 64 + b) * 4 + w] = o;
    }
}

__global__ __launch_bounds__(128)
void crf_combine(const float* __restrict__ wsV, const int* __restrict__ wsO,
                 const int* __restrict__ wsMo, const _Float16* __restrict__ wsMh,
                 float* __restrict__ out)
{
    const int b = blockIdx.x;
    const int j = threadIdx.x;   // 0..127
    __shared__ float stage[128];
    __shared__ float redw[2];

    int o10 = wsMo[(0 * 64 + b) * 4 + 0], o11 = wsMo[(0 * 64 + b) * 4 + 1];
    int o12 = wsMo[(0 * 64 + b) * 4 + 2], o13 = wsMo[(0 * 64 + b) * 4 + 3];
    int o20 = wsMo[(1 * 64 + b) * 4 + 0], o21 = wsMo[(1 * 64 + b) * 4 + 1];
    int o22 = wsMo[(1 * 64 + b) * 4 + 2], o23 = wsMo[(1 * 64 + b) * 4 + 3];
    int O1 = max(max(o10, o11), max(o12, o13));
    int O2 = max(max(o20, o21), max(o22, o23));

    float al = wsV[(size_t)(0 * 64 + b) * 128 + j];
    int r1 = wsMo[(0 * 64 + b) * 4 + (j >> 5)];
    stage[j] = al * __builtin_amdgcn_exp2f((float)(r1 - O1));
    __syncthreads();

    float v1 = 0.f;
    const _Float16* M1 = wsMh + (size_t)(0 * 64 + b) * 128 * 128;
    #pragma unroll 8
    for (int i = 0; i < 128; ++i)
        v1 += stage[i] * (float)M1[(size_t)i * 128 + j];
    __syncthreads();

    int r2 = wsMo[(1 * 64 + b) * 4 + (j >> 5)];
    stage[j] = v1 * __builtin_amdgcn_exp2f((float)(r2 - O2));
    __syncthreads();

    float v2 = 0.f;
    const _Float16* M2 = wsMh + (size_t)(1 * 64 + b) * 128 * 128;
    #pragma unroll 8
    for (int i = 0; i < 128; ++i)
        v2 += stage[i] * (float)M2[(size_t)i * 128 + j];

    float term = v2 * wsV[(size_t)(1 * 64 + b) * 128 + j];
    #pragma unroll
    for (int s = 1; s < 64; s <<= 1) term += __shfl_xor(term, s);
    if ((j & 63) == 0) redw[j >> 6] = term;
    __syncthreads();
    if (j == 0) {
        float V = redw[0] + redw[1];
        out[b] = LN2 * ((float)(wsO[b] + wsO[64 + b] + O1 + O2) +
                        __builtin_amdgcn_logf(V));
    }
}

extern "C" void kernel_launch(void* const* d_in, const int* in_sizes, int n_in,
                              void* d_out, int out_size, void* d_ws, size_t ws_size,
                              hipStream_t stream) {
    const float* emissions   = (const float*)d_in[0];
    const float* transitions = (const float*)d_in[1];
    const float* start_t     = (const float*)d_in[2];
    const float* end_t       = (const float*)d_in[3];
    const int*   lengths     = (const int*)d_in[4];
    float* out = (float*)d_out;

    float*    wsV  = (float*)d_ws;                          // 65536 B
    int*      wsO  = (int*)((char*)d_ws + 65536);           // 512 B
    int*      wsMo = (int*)((char*)d_ws + 66048);           // 2048 B
    _Float16* wsMh = (_Float16*)((char*)d_ws + 68096);      // 4 MB

    crf_fused<<<dim3(256), dim3(256), 0, stream>>>(
        emissions, transitions, start_t, end_t, lengths, wsV, wsO, wsMo, wsMh);
    crf_combine<<<dim3(64), dim3(128), 0, stream>>>(wsV, wsO, wsMo, wsMh, out);
}